// Round 1
// baseline (512.345 us; speedup 1.0000x reference)
//
#include <hip/hip_runtime.h>
#include <hip/hip_bf16.h>
#include <math.h>

#define B_  8
#define T_  2048
#define E_  1024
#define H_  128
#define BT_ (B_*T_)

// ---------------------------------------------------------------------------
// Projection GEMM: out_w[t][h] = sum_e x[t][e] * W_w[e][h]
// grid: (BT_/64, 1, 3)  block: 256
// Tiling: 64 rows x 128 cols per block, K-chunks of 64 staged in LDS.
// Per-thread register tile: 8 rows x 4 cols.
// ---------------------------------------------------------------------------
__global__ __launch_bounds__(256) void proj_kernel(
    const float* __restrict__ x,
    const float* __restrict__ Wk,
    const float* __restrict__ Wq,
    const float* __restrict__ Wv,
    float* __restrict__ k_out,
    float* __restrict__ q_out,
    float* __restrict__ v_out)
{
    __shared__ float xs[64][68];    // +4 pad: 2-way (free) bank aliasing on row reads
    __shared__ float Wc[64][128];

    const int row0 = blockIdx.x * 64;
    const int w    = blockIdx.z;
    const float* __restrict__ W = (w == 0) ? Wk : (w == 1) ? Wq : Wv;
    float* __restrict__ out     = (w == 0) ? k_out : (w == 1) ? q_out : v_out;

    const int tid = threadIdx.x;
    const int tr  = tid >> 5;   // 0..7  (row group)
    const int tc  = tid & 31;   // 0..31 (col group, 4 cols each)

    float acc[8][4];
    #pragma unroll
    for (int i = 0; i < 8; ++i)
        #pragma unroll
        for (int c = 0; c < 4; ++c) acc[i][c] = 0.f;

    for (int ek = 0; ek < 16; ++ek) {
        // stage x chunk: 64 rows x 64 e  (1024 float4, 4 per thread)
        #pragma unroll
        for (int t = 0; t < 4; ++t) {
            int idx = tid + t * 256;          // 0..1023
            int r = idx >> 4, e4 = idx & 15;
            float4 val = *reinterpret_cast<const float4*>(
                &x[(size_t)(row0 + r) * E_ + ek * 64 + e4 * 4]);
            *reinterpret_cast<float4*>(&xs[r][e4 * 4]) = val;
        }
        // stage W chunk: 64 e x 128 h  (2048 float4, 8 per thread)
        #pragma unroll
        for (int t = 0; t < 8; ++t) {
            int idx = tid + t * 256;          // 0..2047
            int e = idx >> 5, c4 = idx & 31;
            float4 val = *reinterpret_cast<const float4*>(
                &W[(size_t)(ek * 64 + e) * H_ + c4 * 4]);
            *reinterpret_cast<float4*>(&Wc[e][c4 * 4]) = val;
        }
        __syncthreads();

        #pragma unroll
        for (int e4 = 0; e4 < 16; ++e4) {
            float4 wv[4];
            #pragma unroll
            for (int j = 0; j < 4; ++j)
                wv[j] = *reinterpret_cast<const float4*>(&Wc[e4 * 4 + j][tc * 4]);
            #pragma unroll
            for (int i = 0; i < 8; ++i) {
                float4 xv = *reinterpret_cast<const float4*>(&xs[tr * 8 + i][e4 * 4]);
                const float xe[4] = {xv.x, xv.y, xv.z, xv.w};
                #pragma unroll
                for (int j = 0; j < 4; ++j) {
                    const float* wp = reinterpret_cast<const float*>(&wv[j]);
                    #pragma unroll
                    for (int c = 0; c < 4; ++c)
                        acc[i][c] = fmaf(xe[j], wp[c], acc[i][c]);
                }
            }
        }
        __syncthreads();
    }

    #pragma unroll
    for (int i = 0; i < 8; ++i) {
        float4 o4 = make_float4(acc[i][0], acc[i][1], acc[i][2], acc[i][3]);
        *reinterpret_cast<float4*>(
            &out[(size_t)(row0 + tr * 8 + i) * H_ + tc * 4]) = o4;
    }
}

// ---------------------------------------------------------------------------
// Flash attention (fp32, causal, online softmax)
// grid: (T_/16, B_)  block: 256
// QB=16 query rows per block, SB=32 keys per tile.
// thread = (qr = tid&15, g = tid>>4).  QK: g = s-group (2 scores).
// PV: g = h-group (8 h each).
// ---------------------------------------------------------------------------
__global__ __launch_bounds__(256) void attn_kernel(
    const float* __restrict__ q_ws,
    const float* __restrict__ k_ws,
    const float* __restrict__ v_ws,
    float* __restrict__ out)
{
    __shared__ float q_t[16][132];   // +4 pad
    __shared__ float k_t[32][132];   // +4 pad (multi-row reads in QK)
    __shared__ float v_t[32][128];   // single-row reads in PV: no pad needed
    __shared__ float Sm[16][33];     // scores -> P
    __shared__ float row_m[16], row_l[16], row_c[16];

    const int q0  = blockIdx.x * 16;
    const int b   = blockIdx.y;
    const int tid = threadIdx.x;
    const size_t base = (size_t)b * T_ * H_;

    // stage q tile (512 float4, 2 per thread)
    #pragma unroll
    for (int t = 0; t < 2; ++t) {
        int idx = tid + t * 256;      // 0..511
        int r = idx >> 5, c4 = idx & 31;
        *reinterpret_cast<float4*>(&q_t[r][c4 * 4]) =
            *reinterpret_cast<const float4*>(
                &q_ws[base + (size_t)(q0 + r) * H_ + c4 * 4]);
    }
    if (tid < 16) { row_m[tid] = -INFINITY; row_l[tid] = 0.f; }

    float o[8];
    #pragma unroll
    for (int t = 0; t < 8; ++t) o[t] = 0.f;

    const int qr = tid & 15;
    const int g  = tid >> 4;          // 0..15

    const int nt = (q0 + 15) / 32 + 1;   // causal: s tiles 0 .. (q0+15)/32
    for (int st = 0; st < nt; ++st) {
        const int s0 = st * 32;
        __syncthreads();   // protect k_t/v_t (prev PV) and q_t/row_m init

        // stage k,v tiles (1024 float4 each, 4 per thread)
        #pragma unroll
        for (int t = 0; t < 4; ++t) {
            int idx = tid + t * 256;  // 0..1023
            int r = idx >> 5, c4 = idx & 31;
            *reinterpret_cast<float4*>(&k_t[r][c4 * 4]) =
                *reinterpret_cast<const float4*>(
                    &k_ws[base + (size_t)(s0 + r) * H_ + c4 * 4]);
            *reinterpret_cast<float4*>(&v_t[r][c4 * 4]) =
                *reinterpret_cast<const float4*>(
                    &v_ws[base + (size_t)(s0 + r) * H_ + c4 * 4]);
        }
        __syncthreads();

        // ---- QK^T: thread computes S[qr][g*2 .. g*2+1] ----
        float sc[2] = {0.f, 0.f};
        #pragma unroll 4
        for (int e4 = 0; e4 < 32; ++e4) {
            float4 qv = *reinterpret_cast<const float4*>(&q_t[qr][e4 * 4]);
            #pragma unroll
            for (int j = 0; j < 2; ++j) {
                float4 kv = *reinterpret_cast<const float4*>(&k_t[g * 2 + j][e4 * 4]);
                sc[j] = fmaf(qv.x, kv.x, sc[j]);
                sc[j] = fmaf(qv.y, kv.y, sc[j]);
                sc[j] = fmaf(qv.z, kv.z, sc[j]);
                sc[j] = fmaf(qv.w, kv.w, sc[j]);
            }
        }
        const float scale = 0.088388347648318447f;  // 1/sqrt(128)
        #pragma unroll
        for (int j = 0; j < 2; ++j) {
            int s_glob = s0 + g * 2 + j;
            float v = sc[j] * scale;
            Sm[qr][g * 2 + j] = (s_glob <= q0 + qr) ? v : -INFINITY;
        }
        __syncthreads();

        // ---- online softmax stats + P = exp(S - m), wave 0 only ----
        if (tid < 64) {
            int row = tid & 15, part = tid >> 4, bs = part * 8;
            float mx = -INFINITY;
            #pragma unroll
            for (int i = 0; i < 8; ++i) mx = fmaxf(mx, Sm[row][bs + i]);
            mx = fmaxf(mx, __shfl_xor(mx, 16));
            mx = fmaxf(mx, __shfl_xor(mx, 32));
            float m_old = row_m[row];
            float m_new = fmaxf(m_old, mx);
            float sum = 0.f;
            #pragma unroll
            for (int i = 0; i < 8; ++i) {
                float p = __expf(Sm[row][bs + i] - m_new);
                Sm[row][bs + i] = p;
                sum += p;
            }
            sum += __shfl_xor(sum, 16);
            sum += __shfl_xor(sum, 32);
            if (part == 0) {
                float c = __expf(m_old - m_new);
                row_c[row] = c;
                row_m[row] = m_new;
                row_l[row] = row_l[row] * c + sum;
            }
        }
        __syncthreads();

        // ---- PV: thread owns o[qr][g*8 .. g*8+7] ----
        float c = row_c[qr];
        #pragma unroll
        for (int t = 0; t < 8; ++t) o[t] *= c;
        #pragma unroll 4
        for (int s = 0; s < 32; ++s) {
            float p = Sm[qr][s];
            float4 v0 = *reinterpret_cast<const float4*>(&v_t[s][g * 8]);
            float4 v1 = *reinterpret_cast<const float4*>(&v_t[s][g * 8 + 4]);
            o[0] = fmaf(p, v0.x, o[0]);
            o[1] = fmaf(p, v0.y, o[1]);
            o[2] = fmaf(p, v0.z, o[2]);
            o[3] = fmaf(p, v0.w, o[3]);
            o[4] = fmaf(p, v1.x, o[4]);
            o[5] = fmaf(p, v1.y, o[5]);
            o[6] = fmaf(p, v1.z, o[6]);
            o[7] = fmaf(p, v1.w, o[7]);
        }
    }

    const float inv = 1.f / row_l[qr];
    float4 o0 = make_float4(o[0] * inv, o[1] * inv, o[2] * inv, o[3] * inv);
    float4 o1 = make_float4(o[4] * inv, o[5] * inv, o[6] * inv, o[7] * inv);
    float* op = &out[base + (size_t)(q0 + qr) * H_ + g * 8];
    *reinterpret_cast<float4*>(op)     = o0;
    *reinterpret_cast<float4*>(op + 4) = o1;
}

// ---------------------------------------------------------------------------
extern "C" void kernel_launch(void* const* d_in, const int* in_sizes, int n_in,
                              void* d_out, int out_size, void* d_ws, size_t ws_size,
                              hipStream_t stream) {
    const float* x  = (const float*)d_in[0];
    const float* Wk = (const float*)d_in[1];   // setup_inputs order: x, Wk, Wq, Wv
    const float* Wq = (const float*)d_in[2];
    const float* Wv = (const float*)d_in[3];
    float* out = (float*)d_out;

    // workspace: k, q, v projections (fp32), 3 * 16384 * 128 * 4B = 24 MB
    float* k_ws = (float*)d_ws;
    float* q_ws = k_ws + (size_t)BT_ * H_;
    float* v_ws = q_ws + (size_t)BT_ * H_;

    dim3 pgrid(BT_ / 64, 1, 3);    // z: 0=k, 1=q, 2=v
    proj_kernel<<<pgrid, 256, 0, stream>>>(x, Wk, Wq, Wv, k_ws, q_ws, v_ws);

    dim3 agrid(T_ / 16, B_);
    attn_kernel<<<agrid, 256, 0, stream>>>(q_ws, k_ws, v_ws, out);
}

// Round 4
// 291.231 us; speedup vs baseline: 1.7592x; 1.7592x over previous
//
#include <hip/hip_runtime.h>
#include <hip/hip_bf16.h>
#include <math.h>

#define B_  8
#define T_  2048
#define E_  1024
#define H_  128
#define BT_ (B_*T_)
#define TH_ (T_*H_)

typedef unsigned short u16;
typedef __attribute__((ext_vector_type(8))) unsigned short u16x8;  // 16B
typedef __attribute__((ext_vector_type(8))) short bf16x8;          // MFMA A/B frag
typedef __attribute__((ext_vector_type(4))) float f32x4;           // MFMA C/D frag

__device__ __forceinline__ u16 f2bf(float f) {
    union { float f; unsigned int u; } a;
    a.f = f;
    unsigned int r = a.u + 0x7FFFu + ((a.u >> 16) & 1u);   // RNE
    return (u16)(r >> 16);
}

// ---------------------------------------------------------------------------
// Projection GEMM (fp32 VALU, bf16 out): out[t][h] = x[t][:]·W[:,h]
// grid (BT/64, 1, 3), block 256.  z=0 -> K (row-major), z=1 -> Q (row-major),
// z=2 -> V stored TRANSPOSED as vt[b][h][t]  (per-thread acc columns are
// contiguous in t, so the transposed store is 16B vector stores).
// ---------------------------------------------------------------------------
__global__ __launch_bounds__(256) void proj_kernel(
    const float* __restrict__ x,
    const float* __restrict__ Wk,
    const float* __restrict__ Wq,
    const float* __restrict__ Wv,
    u16* __restrict__ k_out,
    u16* __restrict__ q_out,
    u16* __restrict__ vt_out)
{
    __shared__ float xs[64][68];
    __shared__ float Wc[64][128];

    const int row0 = blockIdx.x * 64;
    const int w    = blockIdx.z;
    const float* __restrict__ W = (w == 0) ? Wk : (w == 1) ? Wq : Wv;

    const int tid = threadIdx.x;
    const int tr  = tid >> 5;   // 0..7
    const int tc  = tid & 31;   // 0..31

    float acc[8][4];
    #pragma unroll
    for (int i = 0; i < 8; ++i)
        #pragma unroll
        for (int c = 0; c < 4; ++c) acc[i][c] = 0.f;

    for (int ek = 0; ek < 16; ++ek) {
        #pragma unroll
        for (int t = 0; t < 4; ++t) {
            int idx = tid + t * 256;
            int r = idx >> 4, e4 = idx & 15;
            *reinterpret_cast<float4*>(&xs[r][e4 * 4]) =
                *reinterpret_cast<const float4*>(
                    &x[(size_t)(row0 + r) * E_ + ek * 64 + e4 * 4]);
        }
        #pragma unroll
        for (int t = 0; t < 8; ++t) {
            int idx = tid + t * 256;
            int e = idx >> 5, c4 = idx & 31;
            *reinterpret_cast<float4*>(&Wc[e][c4 * 4]) =
                *reinterpret_cast<const float4*>(
                    &W[(size_t)(ek * 64 + e) * H_ + c4 * 4]);
        }
        __syncthreads();

        #pragma unroll
        for (int e4 = 0; e4 < 16; ++e4) {
            float4 wv[4];
            #pragma unroll
            for (int j = 0; j < 4; ++j)
                wv[j] = *reinterpret_cast<const float4*>(&Wc[e4 * 4 + j][tc * 4]);
            #pragma unroll
            for (int i = 0; i < 8; ++i) {
                float4 xv = *reinterpret_cast<const float4*>(&xs[tr * 8 + i][e4 * 4]);
                const float xe[4] = {xv.x, xv.y, xv.z, xv.w};
                #pragma unroll
                for (int j = 0; j < 4; ++j) {
                    const float* wp = reinterpret_cast<const float*>(&wv[j]);
                    #pragma unroll
                    for (int c = 0; c < 4; ++c)
                        acc[i][c] = fmaf(xe[j], wp[c], acc[i][c]);
                }
            }
        }
        __syncthreads();
    }

    if (w == 2) {
        // transposed store: vt[b][h = tc*4+c][t = row0 + tr*8 + i]
        const int vb = row0 >> 11;      // row0 / 2048
        const int t0 = row0 & 2047;
        #pragma unroll
        for (int c = 0; c < 4; ++c) {
            u16x8 w8;
            #pragma unroll
            for (int i = 0; i < 8; ++i) w8[i] = f2bf(acc[i][c]);
            *reinterpret_cast<u16x8*>(
                &vt_out[(size_t)vb * TH_ + (size_t)(tc * 4 + c) * T_ + t0 + tr * 8]) = w8;
        }
    } else {
        u16* __restrict__ out = (w == 0) ? k_out : q_out;
        #pragma unroll
        for (int i = 0; i < 8; ++i) {
            ushort4 o;
            o.x = f2bf(acc[i][0]); o.y = f2bf(acc[i][1]);
            o.z = f2bf(acc[i][2]); o.w = f2bf(acc[i][3]);
            *reinterpret_cast<ushort4*>(
                &out[(size_t)(row0 + tr * 8 + i) * H_ + tc * 4]) = o;
        }
    }
}

// ---------------------------------------------------------------------------
// Flash attention, bf16 MFMA 16x16x32, fp32 softmax/accum. Conservative build:
//  - plain reg-staged LDS (no global_load_lds, no tr_read, no inline asm)
//  - K tile  [64 s][136 pad]  (row-major K, contiguous k-frag reads)
//  - V^T tile [128 h][88 pad] (row-major V^T, contiguous v-frag reads)
//  - P round-trip through per-wave [16][88] LDS (compiler-ordered)
// block = 128 threads (2 waves); wave w owns 16 q rows; KV tile = 64.
// ---------------------------------------------------------------------------
__global__ __launch_bounds__(128) void attn_mfma(
    const u16* __restrict__ qg,
    const u16* __restrict__ kg,
    const u16* __restrict__ vtg,
    float* __restrict__ out)
{
    __shared__ __align__(16) u16 Klds[64][136];
    __shared__ __align__(16) u16 Vlds[128][88];
    __shared__ __align__(16) u16 Plds[2][16][88];

    const int tid  = threadIdx.x;
    const int wave = tid >> 6;
    const int lane = tid & 63;
    const int l15  = lane & 15;
    const int g    = lane >> 4;          // 0..3

    // load-balance decode: pair short/long causal spans
    const int idx = blockIdx.x;
    const int qi  = idx & 63;
    const int b   = idx >> 6;
    const int qb  = (qi & 1) ? (63 - (qi >> 1)) : (qi >> 1);
    const int q0  = qb * 32;
    const int qw0 = q0 + wave * 16;
    const size_t gbase = (size_t)b * TH_;

    // Q fragments from global: A[row=l15][k = ks*32 + g*8 + j]
    bf16x8 qf[4];
    #pragma unroll
    for (int ks = 0; ks < 4; ++ks)
        qf[ks] = *reinterpret_cast<const bf16x8*>(
            &qg[gbase + (size_t)(qw0 + l15) * H_ + ks * 32 + g * 8]);

    f32x4 oacc[8];
    #pragma unroll
    for (int ht = 0; ht < 8; ++ht) oacc[ht] = (f32x4){0.f, 0.f, 0.f, 0.f};
    float m_r[4]  = {-INFINITY, -INFINITY, -INFINITY, -INFINITY};
    float lsum[4] = {0.f, 0.f, 0.f, 0.f};

    const u16* kbat  = kg  + gbase;
    const u16* vtbat = vtg + gbase;

    const int nt = (qb >> 1) + 1;
    for (int st = 0; st < nt; ++st) {
        const int s0 = st * 64;
        __syncthreads();                       // prev tile fully consumed

        // ---- stage K tile: 64 s-rows x 128 k, 1024 x 16B chunks ----
        #pragma unroll
        for (int t = 0; t < 8; ++t) {
            int q = tid + t * 128;             // 0..1023
            int s = q >> 4, c = q & 15;
            u16x8 val = *reinterpret_cast<const u16x8*>(
                &kbat[(size_t)(s0 + s) * H_ + c * 8]);
            *reinterpret_cast<u16x8*>(&Klds[s][c * 8]) = val;
        }
        // ---- stage V^T tile: 128 h-rows x 64 s, 1024 x 16B chunks ----
        #pragma unroll
        for (int t = 0; t < 8; ++t) {
            int q = tid + t * 128;             // 0..1023
            int h = q >> 3, c = q & 7;
            u16x8 val = *reinterpret_cast<const u16x8*>(
                &vtbat[(size_t)h * T_ + s0 + c * 8]);
            *reinterpret_cast<u16x8*>(&Vlds[h][c * 8]) = val;
        }
        __syncthreads();                       // staged data visible

        if (s0 > qw0 + 15) continue;           // fully masked for this wave

        // ---- QK^T: S[16q x 64s] as 4 s-tiles of 16x16 ----
        f32x4 sa[4];
        #pragma unroll
        for (int t4 = 0; t4 < 4; ++t4) sa[t4] = (f32x4){0.f, 0.f, 0.f, 0.f};
        #pragma unroll
        for (int ks = 0; ks < 4; ++ks) {
            #pragma unroll
            for (int t4 = 0; t4 < 4; ++t4) {
                bf16x8 kf = *reinterpret_cast<const bf16x8*>(
                    &Klds[t4 * 16 + l15][(ks * 4 + g) * 8]);
                sa[t4] = __builtin_amdgcn_mfma_f32_16x16x32_bf16(
                    qf[ks], kf, sa[t4], 0, 0, 0);
            }
        }

        // ---- online softmax: D layout row=(g*4+r), col=l15 (per t4 tile) ----
        const float scale = 0.088388347648318447f;   // 1/sqrt(128)
        const bool need_mask = (s0 + 63 > qw0);
        float cfac[4];
        #pragma unroll
        for (int r = 0; r < 4; ++r) {
            const int qrow = qw0 + g * 4 + r;
            float sv[4];
            float mx = -INFINITY;
            #pragma unroll
            for (int t4 = 0; t4 < 4; ++t4) {
                float s = sa[t4][r] * scale;
                if (need_mask && (s0 + t4 * 16 + l15 > qrow)) s = -INFINITY;
                sv[t4] = s;
                mx = fmaxf(mx, s);
            }
            mx = fmaxf(mx, __shfl_xor(mx, 1));
            mx = fmaxf(mx, __shfl_xor(mx, 2));
            mx = fmaxf(mx, __shfl_xor(mx, 4));
            mx = fmaxf(mx, __shfl_xor(mx, 8));
            const float mn = fmaxf(m_r[r], mx);
            const float c  = __expf(m_r[r] - mn);
            float sum = 0.f;
            #pragma unroll
            for (int t4 = 0; t4 < 4; ++t4) {
                float p = __expf(sv[t4] - mn);
                sum += p;
                Plds[wave][g * 4 + r][t4 * 16 + l15] = f2bf(p);
            }
            sum += __shfl_xor(sum, 1);
            sum += __shfl_xor(sum, 2);
            sum += __shfl_xor(sum, 4);
            sum += __shfl_xor(sum, 8);
            lsum[r] = lsum[r] * c + sum;
            m_r[r]  = mn;
            cfac[r] = c;
        }
        #pragma unroll
        for (int ht = 0; ht < 8; ++ht) {
            #pragma unroll
            for (int r = 0; r < 4; ++r) oacc[ht][r] *= cfac[r];
        }

        // ---- PV: O[16q x 128h] += P[16q x 64s] · V[64s x 128h] ----
        // A = P: row=l15, k = ks2*32 + g*8 + j   (per-wave Plds, compiler-ordered)
        // B = V^T rows: lane reads Vlds[ht*16+l15][(ks2*4+g)*8 .. +8]
        #pragma unroll
        for (int ks2 = 0; ks2 < 2; ++ks2) {
            bf16x8 pa = *reinterpret_cast<const bf16x8*>(
                &Plds[wave][l15][ks2 * 32 + g * 8]);
            #pragma unroll
            for (int ht = 0; ht < 8; ++ht) {
                bf16x8 vf = *reinterpret_cast<const bf16x8*>(
                    &Vlds[ht * 16 + l15][(ks2 * 4 + g) * 8]);
                oacc[ht] = __builtin_amdgcn_mfma_f32_16x16x32_bf16(
                    pa, vf, oacc[ht], 0, 0, 0);
            }
        }
    }

    // ---- epilogue: rows qw0+g*4+r, cols ht*16+l15 ----
    #pragma unroll
    for (int r = 0; r < 4; ++r) {
        const float inv = 1.f / lsum[r];
        float* op = &out[gbase + (size_t)(qw0 + g * 4 + r) * H_];
        #pragma unroll
        for (int ht = 0; ht < 8; ++ht)
            op[ht * 16 + l15] = oacc[ht][r] * inv;
    }
}

// ---------------------------------------------------------------------------
extern "C" void kernel_launch(void* const* d_in, const int* in_sizes, int n_in,
                              void* d_out, int out_size, void* d_ws, size_t ws_size,
                              hipStream_t stream) {
    const float* x  = (const float*)d_in[0];
    const float* Wk = (const float*)d_in[1];
    const float* Wq = (const float*)d_in[2];
    const float* Wv = (const float*)d_in[3];
    float* out = (float*)d_out;

    // workspace: k, q (row-major) + v^T, all bf16: 3 * 16384*128 * 2B = 12 MB
    u16* k_ws  = (u16*)d_ws;
    u16* q_ws  = k_ws + (size_t)BT_ * H_;
    u16* vt_ws = q_ws + (size_t)BT_ * H_;

    dim3 pgrid(BT_ / 64, 1, 3);    // z: 0=k, 1=q, 2=v^T
    proj_kernel<<<pgrid, 256, 0, stream>>>(x, Wk, Wq, Wv, k_ws, q_ws, vt_ws);

    attn_mfma<<<dim3(512), 128, 0, stream>>>(q_ws, k_ws, vt_ws, out);
}

// Round 5
// 114.961 us; speedup vs baseline: 4.4567x; 2.5333x over previous
//
#include <hip/hip_runtime.h>
#include <hip/hip_bf16.h>
#include <math.h>

#define B_  8
#define T_  2048
#define E_  1024
#define H_  128
#define BT_ (B_*T_)
#define TH_ (T_*H_)

typedef unsigned short u16;
typedef __attribute__((ext_vector_type(8))) unsigned short u16x8;  // 16B
typedef __attribute__((ext_vector_type(8))) short bf16x8;          // MFMA A/B frag
typedef __attribute__((ext_vector_type(4))) float f32x4;           // MFMA C/D frag

__device__ __forceinline__ u16 f2bf(float f) {
    union { float f; unsigned int u; } a;
    a.f = f;
    unsigned int r = a.u + 0x7FFFu + ((a.u >> 16) & 1u);   // RNE
    return (u16)(r >> 16);
}

// ---------------------------------------------------------------------------
// prep: W[e][h] fp32  ->  Wt[w][h][e] bf16   (B-operand wants [n=h][k=e] rows)
// grid: 24 blocks (w*8 + e-tile), 256 thr. LDS-tiled 128x128 transpose.
// ---------------------------------------------------------------------------
__global__ __launch_bounds__(256) void prep_kernel(
    const float* __restrict__ Wk,
    const float* __restrict__ Wq,
    const float* __restrict__ Wv,
    u16* __restrict__ Wt)
{
    __shared__ u16 Tl[128][136];           // stride 136 u16 = 272B (16B-mult)

    const int w  = blockIdx.x >> 3;        // 0..2
    const int et = blockIdx.x & 7;         // 0..7 (e-tile of 128)
    const float* __restrict__ W = (w == 0) ? Wk : (w == 1) ? Wq : Wv;
    const int tid = threadIdx.x;

    // load 128e x 128h fp32 tile, convert, write transposed into LDS
    #pragma unroll
    for (int i = 0; i < 16; ++i) {
        int q = tid + i * 256;             // 0..4095 float4 chunks
        int e = q >> 5, hc = q & 31;       // e:0..127, hc:0..31
        float4 v = *reinterpret_cast<const float4*>(
            &W[(size_t)(et * 128 + e) * H_ + hc * 4]);
        Tl[hc * 4 + 0][e] = f2bf(v.x);
        Tl[hc * 4 + 1][e] = f2bf(v.y);
        Tl[hc * 4 + 2][e] = f2bf(v.z);
        Tl[hc * 4 + 3][e] = f2bf(v.w);
    }
    __syncthreads();

    // store Wt[w][h][et*128 + e] coalesced
    #pragma unroll
    for (int i = 0; i < 8; ++i) {
        int q = tid + i * 256;             // 0..2047 u16x8 chunks
        int h = q >> 4, ec = q & 15;
        *reinterpret_cast<u16x8*>(
            &Wt[(size_t)w * (H_ * E_) + (size_t)h * E_ + et * 128 + ec * 8]) =
            *reinterpret_cast<const u16x8*>(&Tl[h][ec * 8]);
    }
}

// ---------------------------------------------------------------------------
// proj_mfma: out[t][h] = x[t][:] . W[:,h]  via bf16 MFMA 16x16x32.
// grid (BT/64, 1, 3), block 256 (4 waves, 2m x 2n; each wave 32x64 out).
// BM=64, BN=128(=H), BK=64, 16 K-steps. fp32->bf16 conversion fused in A-stage.
// z=0 -> K [t][h], z=1 -> Q [t][h], z=2 -> V^T [h][t] (coalesced via LDS bounce).
// ---------------------------------------------------------------------------
__global__ __launch_bounds__(256) void proj_mfma(
    const float* __restrict__ x,
    const u16* __restrict__ Wt,
    u16* __restrict__ k_out,
    u16* __restrict__ q_out,
    u16* __restrict__ vt_out)
{
    __shared__ __align__(16) u16 S[13824];   // As[64][72] @0 | Bs[128][72] @4608
    u16* As = S;                              // row stride 72 u16 (144B)
    u16* Bs = S + 4608;                       // row stride 72 u16
    // epilogue overlays: Cs [64][136] (w<2) or [128][72] (w==2), both <= 13824

    const int row0 = blockIdx.x * 64;
    const int w    = blockIdx.z;
    const int tid  = threadIdx.x;
    const int wave = tid >> 6;
    const int lane = tid & 63;
    const int l15  = lane & 15;
    const int g    = lane >> 4;
    const int wm   = wave >> 1;     // 0..1 (m half)
    const int wn   = wave & 1;      // 0..1 (n half)

    f32x4 acc[2][4];
    #pragma unroll
    for (int m = 0; m < 2; ++m)
        #pragma unroll
        for (int n = 0; n < 4; ++n) acc[m][n] = (f32x4){0.f, 0.f, 0.f, 0.f};

    const u16* WtW = Wt + (size_t)w * (H_ * E_);

    for (int ek = 0; ek < 16; ++ek) {
        __syncthreads();   // prev step's frag reads done
        // ---- stage A: x[row0..+64)[ek*64..+64) fp32 -> bf16 LDS ----
        #pragma unroll
        for (int i = 0; i < 4; ++i) {
            int q = tid + i * 256;         // 0..1023 float4 chunks
            int r = q >> 4, c4 = q & 15;   // r:0..63, c4:0..15
            float4 v = *reinterpret_cast<const float4*>(
                &x[(size_t)(row0 + r) * E_ + ek * 64 + c4 * 4]);
            ushort4 h4;
            h4.x = f2bf(v.x); h4.y = f2bf(v.y);
            h4.z = f2bf(v.z); h4.w = f2bf(v.w);
            *reinterpret_cast<ushort4*>(&As[r * 72 + c4 * 4]) = h4;
        }
        // ---- stage B: Wt rows [h][ek*64..+64) bf16 copy ----
        #pragma unroll
        for (int i = 0; i < 4; ++i) {
            int q = tid + i * 256;         // 0..1023 u16x8 chunks
            int h = q >> 3, c8 = q & 7;
            *reinterpret_cast<u16x8*>(&Bs[h * 72 + c8 * 8]) =
                *reinterpret_cast<const u16x8*>(
                    &WtW[(size_t)h * E_ + ek * 64 + c8 * 8]);
        }
        __syncthreads();

        // ---- MFMA: acc[m][n] += A(32xk) . B(64xk) ----
        #pragma unroll
        for (int kk = 0; kk < 2; ++kk) {
            bf16x8 af[2];
            #pragma unroll
            for (int m = 0; m < 2; ++m)
                af[m] = *reinterpret_cast<const bf16x8*>(
                    &As[(wm * 32 + m * 16 + l15) * 72 + kk * 32 + g * 8]);
            #pragma unroll
            for (int n = 0; n < 4; ++n) {
                bf16x8 bfr = *reinterpret_cast<const bf16x8*>(
                    &Bs[(wn * 64 + n * 16 + l15) * 72 + kk * 32 + g * 8]);
                #pragma unroll
                for (int m = 0; m < 2; ++m)
                    acc[m][n] = __builtin_amdgcn_mfma_f32_16x16x32_bf16(
                        af[m], bfr, acc[m][n], 0, 0, 0);
            }
        }
    }
    __syncthreads();   // done with As/Bs; reuse as Cs

    if (w < 2) {
        // bounce Cs[64][136]: row=t_local, col=h  (stride 136 u16 = 272B)
        #pragma unroll
        for (int m = 0; m < 2; ++m)
            #pragma unroll
            for (int n = 0; n < 4; ++n)
                #pragma unroll
                for (int r = 0; r < 4; ++r)
                    S[(wm * 32 + m * 16 + g * 4 + r) * 136 +
                      wn * 64 + n * 16 + l15] = f2bf(acc[m][n][r]);
        __syncthreads();
        u16* __restrict__ outp = (w == 0) ? k_out : q_out;
        #pragma unroll
        for (int i = 0; i < 4; ++i) {
            int q = tid + i * 256;          // 0..1023: 64 rows x 16 chunks
            int r = q >> 4, c8 = q & 15;
            *reinterpret_cast<u16x8*>(
                &outp[(size_t)(row0 + r) * H_ + c8 * 8]) =
                *reinterpret_cast<const u16x8*>(&S[r * 136 + c8 * 8]);
        }
    } else {
        // bounce Cs[128][72]: row=h, col=t_local (acc's 4 rows are 4 consec t)
        #pragma unroll
        for (int m = 0; m < 2; ++m)
            #pragma unroll
            for (int n = 0; n < 4; ++n) {
                ushort4 h4;
                h4.x = f2bf(acc[m][n][0]); h4.y = f2bf(acc[m][n][1]);
                h4.z = f2bf(acc[m][n][2]); h4.w = f2bf(acc[m][n][3]);
                *reinterpret_cast<ushort4*>(
                    &S[(wn * 64 + n * 16 + l15) * 72 +
                       wm * 32 + m * 16 + g * 4]) = h4;
            }
        __syncthreads();
        const int vb = row0 >> 11;          // batch
        const int t0 = row0 & 2047;
        #pragma unroll
        for (int i = 0; i < 4; ++i) {
            int q = tid + i * 256;          // 0..1023: 128 h x 8 chunks
            int h = q >> 3, c8 = q & 7;
            *reinterpret_cast<u16x8*>(
                &vt_out[(size_t)vb * TH_ + (size_t)h * T_ + t0 + c8 * 8]) =
                *reinterpret_cast<const u16x8*>(&S[h * 72 + c8 * 8]);
        }
    }
}

// ---------------------------------------------------------------------------
// Flash attention, bf16 MFMA 16x16x32, fp32 softmax/accum. (verified round 4)
// ---------------------------------------------------------------------------
__global__ __launch_bounds__(128) void attn_mfma(
    const u16* __restrict__ qg,
    const u16* __restrict__ kg,
    const u16* __restrict__ vtg,
    float* __restrict__ out)
{
    __shared__ __align__(16) u16 Klds[64][136];
    __shared__ __align__(16) u16 Vlds[128][88];
    __shared__ __align__(16) u16 Plds[2][16][88];

    const int tid  = threadIdx.x;
    const int wave = tid >> 6;
    const int lane = tid & 63;
    const int l15  = lane & 15;
    const int g    = lane >> 4;          // 0..3

    const int idx = blockIdx.x;
    const int qi  = idx & 63;
    const int b   = idx >> 6;
    const int qb  = (qi & 1) ? (63 - (qi >> 1)) : (qi >> 1);
    const int q0  = qb * 32;
    const int qw0 = q0 + wave * 16;
    const size_t gbase = (size_t)b * TH_;

    bf16x8 qf[4];
    #pragma unroll
    for (int ks = 0; ks < 4; ++ks)
        qf[ks] = *reinterpret_cast<const bf16x8*>(
            &qg[gbase + (size_t)(qw0 + l15) * H_ + ks * 32 + g * 8]);

    f32x4 oacc[8];
    #pragma unroll
    for (int ht = 0; ht < 8; ++ht) oacc[ht] = (f32x4){0.f, 0.f, 0.f, 0.f};
    float m_r[4]  = {-INFINITY, -INFINITY, -INFINITY, -INFINITY};
    float lsum[4] = {0.f, 0.f, 0.f, 0.f};

    const u16* kbat  = kg  + gbase;
    const u16* vtbat = vtg + gbase;

    const int nt = (qb >> 1) + 1;
    for (int st = 0; st < nt; ++st) {
        const int s0 = st * 64;
        __syncthreads();

        #pragma unroll
        for (int t = 0; t < 8; ++t) {
            int q = tid + t * 128;
            int s = q >> 4, c = q & 15;
            u16x8 val = *reinterpret_cast<const u16x8*>(
                &kbat[(size_t)(s0 + s) * H_ + c * 8]);
            *reinterpret_cast<u16x8*>(&Klds[s][c * 8]) = val;
        }
        #pragma unroll
        for (int t = 0; t < 8; ++t) {
            int q = tid + t * 128;
            int h = q >> 3, c = q & 7;
            u16x8 val = *reinterpret_cast<const u16x8*>(
                &vtbat[(size_t)h * T_ + s0 + c * 8]);
            *reinterpret_cast<u16x8*>(&Vlds[h][c * 8]) = val;
        }
        __syncthreads();

        if (s0 > qw0 + 15) continue;

        f32x4 sa[4];
        #pragma unroll
        for (int t4 = 0; t4 < 4; ++t4) sa[t4] = (f32x4){0.f, 0.f, 0.f, 0.f};
        #pragma unroll
        for (int ks = 0; ks < 4; ++ks) {
            #pragma unroll
            for (int t4 = 0; t4 < 4; ++t4) {
                bf16x8 kf = *reinterpret_cast<const bf16x8*>(
                    &Klds[t4 * 16 + l15][(ks * 4 + g) * 8]);
                sa[t4] = __builtin_amdgcn_mfma_f32_16x16x32_bf16(
                    qf[ks], kf, sa[t4], 0, 0, 0);
            }
        }

        const float scale = 0.088388347648318447f;
        const bool need_mask = (s0 + 63 > qw0);
        float cfac[4];
        #pragma unroll
        for (int r = 0; r < 4; ++r) {
            const int qrow = qw0 + g * 4 + r;
            float sv[4];
            float mx = -INFINITY;
            #pragma unroll
            for (int t4 = 0; t4 < 4; ++t4) {
                float s = sa[t4][r] * scale;
                if (need_mask && (s0 + t4 * 16 + l15 > qrow)) s = -INFINITY;
                sv[t4] = s;
                mx = fmaxf(mx, s);
            }
            mx = fmaxf(mx, __shfl_xor(mx, 1));
            mx = fmaxf(mx, __shfl_xor(mx, 2));
            mx = fmaxf(mx, __shfl_xor(mx, 4));
            mx = fmaxf(mx, __shfl_xor(mx, 8));
            const float mn = fmaxf(m_r[r], mx);
            const float c  = __expf(m_r[r] - mn);
            float sum = 0.f;
            #pragma unroll
            for (int t4 = 0; t4 < 4; ++t4) {
                float p = __expf(sv[t4] - mn);
                sum += p;
                Plds[wave][g * 4 + r][t4 * 16 + l15] = f2bf(p);
            }
            sum += __shfl_xor(sum, 1);
            sum += __shfl_xor(sum, 2);
            sum += __shfl_xor(sum, 4);
            sum += __shfl_xor(sum, 8);
            lsum[r] = lsum[r] * c + sum;
            m_r[r]  = mn;
            cfac[r] = c;
        }
        #pragma unroll
        for (int ht = 0; ht < 8; ++ht) {
            #pragma unroll
            for (int r = 0; r < 4; ++r) oacc[ht][r] *= cfac[r];
        }

        #pragma unroll
        for (int ks2 = 0; ks2 < 2; ++ks2) {
            bf16x8 pa = *reinterpret_cast<const bf16x8*>(
                &Plds[wave][l15][ks2 * 32 + g * 8]);
            #pragma unroll
            for (int ht = 0; ht < 8; ++ht) {
                bf16x8 vf = *reinterpret_cast<const bf16x8*>(
                    &Vlds[ht * 16 + l15][(ks2 * 4 + g) * 8]);
                oacc[ht] = __builtin_amdgcn_mfma_f32_16x16x32_bf16(
                    pa, vf, oacc[ht], 0, 0, 0);
            }
        }
    }

    #pragma unroll
    for (int r = 0; r < 4; ++r) {
        const float inv = 1.f / lsum[r];
        float* op = &out[gbase + (size_t)(qw0 + g * 4 + r) * H_];
        #pragma unroll
        for (int ht = 0; ht < 8; ++ht)
            op[ht * 16 + l15] = oacc[ht][r] * inv;
    }
}

// ---------------------------------------------------------------------------
extern "C" void kernel_launch(void* const* d_in, const int* in_sizes, int n_in,
                              void* d_out, int out_size, void* d_ws, size_t ws_size,
                              hipStream_t stream) {
    const float* x  = (const float*)d_in[0];
    const float* Wk = (const float*)d_in[1];
    const float* Wq = (const float*)d_in[2];
    const float* Wv = (const float*)d_in[3];
    float* out = (float*)d_out;

    // ws: k, q (row-major), v^T bf16 (4 MB each) + Wt bf16 (0.75 MB)
    u16* k_ws  = (u16*)d_ws;
    u16* q_ws  = k_ws + (size_t)BT_ * H_;
    u16* vt_ws = q_ws + (size_t)BT_ * H_;
    u16* Wt_ws = vt_ws + (size_t)BT_ * H_;

    prep_kernel<<<dim3(24), 256, 0, stream>>>(Wk, Wq, Wv, Wt_ws);

    dim3 pgrid(BT_ / 64, 1, 3);    // z: 0=k, 1=q, 2=v^T
    proj_mfma<<<pgrid, 256, 0, stream>>>(x, Wt_ws, k_ws, q_ws, vt_ws);

    attn_mfma<<<dim3(512), 128, 0, stream>>>(q_ws, k_ws, vt_ws, out);
}